// Round 6
// baseline (93.172 us; speedup 1.0000x reference)
//
#include <hip/hip_runtime.h>
#include <hip/hip_bf16.h>
#include <math.h>

#define N_ 8192
#define A_ 512
#define D_ 512
#define NN_ 3

// ---------------------------------------------------------------------------
// Fast exact-GELU: erf via Abramowitz-Stegun 7.1.26 (|err| <= 1.5e-7),
// branchless (odd symmetry via copysign). 2 trans ops (rcp, exp2) + ~12 VALU.
// ---------------------------------------------------------------------------
__device__ __forceinline__ float gelu_erf_fast(float x) {
  const float z  = fabsf(x) * 0.70710678118654752440f;   // |x|/sqrt(2)
  const float t  = __builtin_amdgcn_rcpf(fmaf(0.3275911f, z, 1.0f));
  float p = fmaf(1.061405429f, t, -1.453152027f);
  p = fmaf(p, t, 1.421413741f);
  p = fmaf(p, t, -0.284496736f);
  p = fmaf(p, t, 0.254829592f);
  p = p * t;
  const float e  = exp2f(z * z * -1.44269504088896340736f);  // exp(-z^2)
  float erfz = fmaf(-p, e, 1.0f);                            // erf(z), z>=0
  erfz = copysignf(erfz, x);
  return 0.5f * x * (1.0f + erfz);
}

// ---------------------------------------------------------------------------
// Kernel 0: sq[i] = ||a_i||^2. One wave per anchor.
// ---------------------------------------------------------------------------
__global__ __launch_bounds__(64) void sq_kernel(
    const float* __restrict__ anchors, float* __restrict__ sq) {
  const int i = blockIdx.x;
  const int l = threadIdx.x;
  const float4* a = reinterpret_cast<const float4*>(anchors + (size_t)i * D_);
  float s = 0.f;
  for (int k = l; k < D_ / 4; k += 64) {
    float4 v = a[k];
    s += v.x * v.x + v.y * v.y + v.z * v.z + v.w * v.w;
  }
#pragma unroll
  for (int d = 32; d > 0; d >>= 1) s += __shfl_down(s, d);
  if (l == 0) sq[i] = s;
}

// ---------------------------------------------------------------------------
// Kernel 1: G = anchors @ anchors^T via LDS-tiled GEMM. (unchanged)
// ---------------------------------------------------------------------------
__global__ __launch_bounds__(256) void gram_tiled_kernel(
    const float* __restrict__ anchors, float* __restrict__ G) {
  __shared__ float At[32][68];
  __shared__ float Bt[32][68];

  const int tx = threadIdx.x;          // 0..15
  const int ty = threadIdx.y;          // 0..15
  const int tid = ty * 16 + tx;
  const int i0 = blockIdx.y * 64;
  const int j0 = blockIdx.x * 64;

  const int r0 = tid >> 3;             // 0..31
  const int c4 = tid & 7;              // 0..7

  float acc[4][4];
#pragma unroll
  for (int m = 0; m < 4; ++m)
#pragma unroll
    for (int n = 0; n < 4; ++n) acc[m][n] = 0.f;

  for (int kt = 0; kt < 16; ++kt) {
    const int kb = kt * 32 + c4 * 4;
    float4 va = *reinterpret_cast<const float4*>(&anchors[(size_t)(i0 + r0) * D_ + kb]);
    float4 vb = *reinterpret_cast<const float4*>(&anchors[(size_t)(i0 + r0 + 32) * D_ + kb]);
    float4 wa = *reinterpret_cast<const float4*>(&anchors[(size_t)(j0 + r0) * D_ + kb]);
    float4 wb = *reinterpret_cast<const float4*>(&anchors[(size_t)(j0 + r0 + 32) * D_ + kb]);
    __syncthreads();
    const int kc = c4 * 4;
    At[kc + 0][r0] = va.x; At[kc + 1][r0] = va.y; At[kc + 2][r0] = va.z; At[kc + 3][r0] = va.w;
    At[kc + 0][r0 + 32] = vb.x; At[kc + 1][r0 + 32] = vb.y; At[kc + 2][r0 + 32] = vb.z; At[kc + 3][r0 + 32] = vb.w;
    Bt[kc + 0][r0] = wa.x; Bt[kc + 1][r0] = wa.y; Bt[kc + 2][r0] = wa.z; Bt[kc + 3][r0] = wa.w;
    Bt[kc + 0][r0 + 32] = wb.x; Bt[kc + 1][r0 + 32] = wb.y; Bt[kc + 2][r0 + 32] = wb.z; Bt[kc + 3][r0 + 32] = wb.w;
    __syncthreads();

#pragma unroll
    for (int kk = 0; kk < 32; ++kk) {
      float4 a = *reinterpret_cast<const float4*>(&At[kk][ty * 4]);
      float4 b = *reinterpret_cast<const float4*>(&Bt[kk][tx * 4]);
      acc[0][0] += a.x * b.x; acc[0][1] += a.x * b.y; acc[0][2] += a.x * b.z; acc[0][3] += a.x * b.w;
      acc[1][0] += a.y * b.x; acc[1][1] += a.y * b.y; acc[1][2] += a.y * b.z; acc[1][3] += a.y * b.w;
      acc[2][0] += a.z * b.x; acc[2][1] += a.z * b.y; acc[2][2] += a.z * b.z; acc[2][3] += a.z * b.w;
      acc[3][0] += a.w * b.x; acc[3][1] += a.w * b.y; acc[3][2] += a.w * b.z; acc[3][3] += a.w * b.w;
    }
  }

#pragma unroll
  for (int m = 0; m < 4; ++m) {
    float4 st;
    st.x = acc[m][0]; st.y = acc[m][1]; st.z = acc[m][2]; st.w = acc[m][3];
    *reinterpret_cast<float4*>(&G[(size_t)(i0 + ty * 4 + m) * A_ + j0 + tx * 4]) = st;
  }
}

// ---------------------------------------------------------------------------
// Kernel 2: per-anchor 3-NN + Cayley-Menger det. One wave per anchor. (unchanged)
// ---------------------------------------------------------------------------
__device__ __forceinline__ void lexmin(float& v, int& j, float ov, int oj) {
  if (ov < v || (ov == v && oj < j)) { v = ov; j = oj; }
}

__global__ __launch_bounds__(64) void nn_det_kernel(
    const float* __restrict__ G, const float* __restrict__ sq,
    float* __restrict__ quality) {
  __shared__ float d2s[16];
  const int i = blockIdx.x;
  const int l = threadIdx.x;
  const float sqi = sq[i];
  const float* Grow = G + (size_t)i * A_;
  const int jb = l * 8;

  float4 g0 = *reinterpret_cast<const float4*>(&Grow[jb]);
  float4 g1 = *reinterpret_cast<const float4*>(&Grow[jb + 4]);
  float4 s0 = *reinterpret_cast<const float4*>(&sq[jb]);
  float4 s1 = *reinterpret_cast<const float4*>(&sq[jb + 4]);

  float dist[8];
  {
    float gg[8] = { g0.x, g0.y, g0.z, g0.w, g1.x, g1.y, g1.z, g1.w };
    float ss[8] = { s0.x, s0.y, s0.z, s0.w, s1.x, s1.y, s1.z, s1.w };
#pragma unroll
    for (int q = 0; q < 8; ++q) {
      float d2 = fmaxf(sqi + ss[q] - 2.f * gg[q], 0.f);
      float dd = sqrtf(d2);
      if (jb + q == i) dd += 1e12f;
      dist[q] = dd;
    }
  }

  int nn[NN_];
#pragma unroll
  for (int r = 0; r < NN_; ++r) {
    float bv = 1e30f;
    int bi = 0x7fffffff;
#pragma unroll
    for (int q = 0; q < 8; ++q) lexmin(bv, bi, dist[q], jb + q);
#pragma unroll
    for (int d = 1; d < 64; d <<= 1) {
      float ov = __shfl_xor(bv, d);
      int oi = __shfl_xor(bi, d);
      lexmin(bv, bi, ov, oi);
    }
    nn[r] = bi;
#pragma unroll
    for (int q = 0; q < 8; ++q)
      if (jb + q == bi) dist[q] = 1e30f;
  }

  if (l < 16) {
    const int p = l >> 2, q = l & 3;
    const int pi = (p == 0) ? i : ((p == 1) ? nn[0] : ((p == 2) ? nn[1] : nn[2]));
    const int qi = (q == 0) ? i : ((q == 1) ? nn[0] : ((q == 2) ? nn[1] : nn[2]));
    float d2f;
    if (p == q) {
      d2f = 0.f;
    } else {
      float g = G[(size_t)pi * A_ + qi];
      d2f = sq[pi] + sq[qi] - 2.f * g;
    }
    d2s[l] = d2f;
  }
  __syncthreads();

  if (l == 0) {
    double M[5][5];
    M[0][0] = 0.0;
    for (int q = 1; q < 5; ++q) { M[0][q] = 1.0; M[q][0] = 1.0; }
    for (int p = 0; p < 4; ++p)
      for (int q = 0; q < 4; ++q)
        M[p + 1][q + 1] = (double)d2s[p * 4 + q];

    double det = 1.0;
    for (int c = 0; c < 5; ++c) {
      int piv = c;
      double mx = fabs(M[c][c]);
      for (int r2 = c + 1; r2 < 5; ++r2) {
        double v = fabs(M[r2][c]);
        if (v > mx) { mx = v; piv = r2; }
      }
      if (piv != c) {
        for (int c2 = 0; c2 < 5; ++c2) { double tmp = M[c][c2]; M[c][c2] = M[piv][c2]; M[piv][c2] = tmp; }
        det = -det;
      }
      double pv = M[c][c];
      det *= pv;
      if (pv == 0.0) break;
      for (int r2 = c + 1; r2 < 5; ++r2) {
        double f = M[r2][c] / pv;
        for (int c2 = c; c2 < 5; ++c2) M[r2][c2] -= f * M[c][c2];
      }
    }
    float raw = (float)det;
    float sg = (raw > 0.f) ? 1.f : ((raw < 0.f) ? -1.f : 0.f);
    quality[i] = sg * logf(fabsf(raw) + 1e-12f);
  }
}

// ---------------------------------------------------------------------------
// Kernel 3: normalize quality -> (q - mean) / max(std_ddof1, 1e-8). 1 block.
// ---------------------------------------------------------------------------
__global__ __launch_bounds__(A_) void norm_cm_kernel(
    const float* __restrict__ quality, float* __restrict__ cmn) {
  __shared__ float red[A_];
  const int t = threadIdx.x;
  float q = quality[t];
  red[t] = q;
  __syncthreads();
  for (int s = A_ / 2; s > 0; s >>= 1) {
    if (t < s) red[t] += red[t + s];
    __syncthreads();
  }
  float mean = red[0] * (1.0f / A_);
  __syncthreads();
  float dq = q - mean;
  red[t] = dq * dq;
  __syncthreads();
  for (int s = A_ / 2; s > 0; s >>= 1) {
    if (t < s) red[t] += red[t + s];
    __syncthreads();
  }
  float sd = sqrtf(red[0] * (1.0f / (A_ - 1)));
  sd = fmaxf(sd, 1e-8f);
  cmn[t] = dq / sd;
}

// ---------------------------------------------------------------------------
// Kernel 4: bucket-histogram stable rank + gate MLP (fast erf) + sigmoid.
// ---------------------------------------------------------------------------
__global__ __launch_bounds__(A_) void gate_kernel_bucket(
    const float* __restrict__ tri, const float* __restrict__ cmn,
    const float* __restrict__ W1, const float* __restrict__ b1,
    const float* __restrict__ W2, const float* __restrict__ b2,
    float* __restrict__ out) {
  __shared__ int hist[256];
  __shared__ int pref[256];
  __shared__ int cursor[256];
  __shared__ unsigned long long sorted[A_];

  const int n = blockIdx.x;
  const int t = threadIdx.x;

  const float ti = tri[(size_t)n * A_ + t];
  const unsigned long long key =
      ((unsigned long long)__float_as_uint(ti) << 9) | (unsigned)t;
  int b = (int)(ti * 128.0f);
  b = (b < 0) ? 0 : ((b > 255) ? 255 : b);

  if (t < 256) { hist[t] = 0; cursor[t] = 0; }
  __syncthreads();
  atomicAdd(&hist[b], 1);
  __syncthreads();

  if (t < 64) {
    const int b4 = t * 4;
    int h0 = hist[b4 + 0], h1 = hist[b4 + 1], h2 = hist[b4 + 2], h3 = hist[b4 + 3];
    int s = h0 + h1 + h2 + h3;
    int incl = s;
#pragma unroll
    for (int d = 1; d < 64; d <<= 1) {
      int u = __shfl_up(incl, d);
      if (t >= d) incl += u;
    }
    int ex = incl - s;
    pref[b4 + 0] = ex;
    pref[b4 + 1] = ex + h0;
    pref[b4 + 2] = ex + h0 + h1;
    pref[b4 + 3] = ex + h0 + h1 + h2;
  }
  __syncthreads();

  const int pos = pref[b] + atomicAdd(&cursor[b], 1);
  sorted[pos] = key;
  __syncthreads();

  const int start = pref[b];
  const int len = hist[b];
  int cnt = start;
  for (int m = 0; m < len; ++m) cnt += (sorted[start + m] < key);
  const float rank = (float)cnt * (1.0f / (A_ - 1));

  const float f0 = cmn[t];
  const float f1 = 1.0f - ti;

  float logit = b2[0];
#pragma unroll
  for (int k = 0; k < 16; ++k) {
    float x = fmaf(W1[k * 3 + 0], f0,
              fmaf(W1[k * 3 + 1], f1,
              fmaf(W1[k * 3 + 2], rank, b1[k])));
    logit = fmaf(W2[k], gelu_erf_fast(x), logit);
  }
  // sigmoid via exp2 + rcp
  const float eneg = exp2f(logit * -1.44269504088896340736f);
  out[(size_t)n * A_ + t] = __builtin_amdgcn_rcpf(1.0f + eneg);
}

// ---------------------------------------------------------------------------
extern "C" void kernel_launch(void* const* d_in, const int* in_sizes, int n_in,
                              void* d_out, int out_size, void* d_ws, size_t ws_size,
                              hipStream_t stream) {
  // inputs: 0 embedding (unused), 1 anchors, 2 tri, 3 W1, 4 b1, 5 W2, 6 b2
  const float* anchors = (const float*)d_in[1];
  const float* tri     = (const float*)d_in[2];
  const float* W1      = (const float*)d_in[3];
  const float* b1      = (const float*)d_in[4];
  const float* W2      = (const float*)d_in[5];
  const float* b2      = (const float*)d_in[6];
  float* out = (float*)d_out;

  float* G       = (float*)d_ws;              // A_*A_ floats (1 MB)
  float* sq      = G + (size_t)A_ * A_;       // A_ floats
  float* quality = sq + A_;                   // A_ floats
  float* cmn     = quality + A_;              // A_ floats

  sq_kernel<<<A_, 64, 0, stream>>>(anchors, sq);
  gram_tiled_kernel<<<dim3(8, 8), dim3(16, 16), 0, stream>>>(anchors, G);
  nn_det_kernel<<<A_, 64, 0, stream>>>(G, sq, quality);
  norm_cm_kernel<<<1, A_, 0, stream>>>(quality, cmn);
  gate_kernel_bucket<<<N_, A_, 0, stream>>>(tri, cmn, W1, b1, W2, b2, out);
}

// Round 7
// 85.374 us; speedup vs baseline: 1.0913x; 1.0913x over previous
//
#include <hip/hip_runtime.h>
#include <hip/hip_bf16.h>
#include <math.h>

#define N_ 8192
#define A_ 512
#define D_ 512
#define NN_ 3
#define KPARTS 4

// ---------------------------------------------------------------------------
// Fast exact-GELU: erf via Abramowitz-Stegun 7.1.26 (|err| <= 1.5e-7).
// ---------------------------------------------------------------------------
__device__ __forceinline__ float gelu_erf_fast(float x) {
  const float z  = fabsf(x) * 0.70710678118654752440f;   // |x|/sqrt(2)
  const float t  = __builtin_amdgcn_rcpf(fmaf(0.3275911f, z, 1.0f));
  float p = fmaf(1.061405429f, t, -1.453152027f);
  p = fmaf(p, t, 1.421413741f);
  p = fmaf(p, t, -0.284496736f);
  p = fmaf(p, t, 0.254829592f);
  p = p * t;
  const float e  = exp2f(z * z * -1.44269504088896340736f);  // exp(-z^2)
  float erfz = fmaf(-p, e, 1.0f);
  erfz = copysignf(erfz, x);
  return 0.5f * x * (1.0f + erfz);
}

// ---------------------------------------------------------------------------
// Kernel 0: sq[i] = ||a_i||^2. One wave per anchor.
// ---------------------------------------------------------------------------
__global__ __launch_bounds__(64) void sq_kernel(
    const float* __restrict__ anchors, float* __restrict__ sq) {
  const int i = blockIdx.x;
  const int l = threadIdx.x;
  const float4* a = reinterpret_cast<const float4*>(anchors + (size_t)i * D_);
  float s = 0.f;
  for (int k = l; k < D_ / 4; k += 64) {
    float4 v = a[k];
    s += v.x * v.x + v.y * v.y + v.z * v.z + v.w * v.w;
  }
#pragma unroll
  for (int d = 32; d > 0; d >>= 1) s += __shfl_down(s, d);
  if (l == 0) sq[i] = s;
}

// ---------------------------------------------------------------------------
// Kernel 1: G_z = anchors(:,Kz) @ anchors(:,Kz)^T for K-part z (4 parts).
// 64x64 tile per block, grid 8x8x4 = 256 blocks (full CU fill).
// ---------------------------------------------------------------------------
__global__ __launch_bounds__(256) void gram_tiled_kernel(
    const float* __restrict__ anchors, float* __restrict__ G) {
  __shared__ float At[32][68];
  __shared__ float Bt[32][68];

  const int tx = threadIdx.x;          // 0..15
  const int ty = threadIdx.y;          // 0..15
  const int tid = ty * 16 + tx;
  const int i0 = blockIdx.y * 64;
  const int j0 = blockIdx.x * 64;
  const int z  = blockIdx.z;
  float* Gz = G + (size_t)z * A_ * A_;

  const int r0 = tid >> 3;             // 0..31
  const int c4 = tid & 7;              // 0..7

  float acc[4][4];
#pragma unroll
  for (int m = 0; m < 4; ++m)
#pragma unroll
    for (int n = 0; n < 4; ++n) acc[m][n] = 0.f;

  for (int kt = z * (16 / KPARTS); kt < (z + 1) * (16 / KPARTS); ++kt) {
    const int kb = kt * 32 + c4 * 4;
    float4 va = *reinterpret_cast<const float4*>(&anchors[(size_t)(i0 + r0) * D_ + kb]);
    float4 vb = *reinterpret_cast<const float4*>(&anchors[(size_t)(i0 + r0 + 32) * D_ + kb]);
    float4 wa = *reinterpret_cast<const float4*>(&anchors[(size_t)(j0 + r0) * D_ + kb]);
    float4 wb = *reinterpret_cast<const float4*>(&anchors[(size_t)(j0 + r0 + 32) * D_ + kb]);
    __syncthreads();
    const int kc = c4 * 4;
    At[kc + 0][r0] = va.x; At[kc + 1][r0] = va.y; At[kc + 2][r0] = va.z; At[kc + 3][r0] = va.w;
    At[kc + 0][r0 + 32] = vb.x; At[kc + 1][r0 + 32] = vb.y; At[kc + 2][r0 + 32] = vb.z; At[kc + 3][r0 + 32] = vb.w;
    Bt[kc + 0][r0] = wa.x; Bt[kc + 1][r0] = wa.y; Bt[kc + 2][r0] = wa.z; Bt[kc + 3][r0] = wa.w;
    Bt[kc + 0][r0 + 32] = wb.x; Bt[kc + 1][r0 + 32] = wb.y; Bt[kc + 2][r0 + 32] = wb.z; Bt[kc + 3][r0 + 32] = wb.w;
    __syncthreads();

#pragma unroll
    for (int kk = 0; kk < 32; ++kk) {
      float4 a = *reinterpret_cast<const float4*>(&At[kk][ty * 4]);
      float4 b = *reinterpret_cast<const float4*>(&Bt[kk][tx * 4]);
      acc[0][0] += a.x * b.x; acc[0][1] += a.x * b.y; acc[0][2] += a.x * b.z; acc[0][3] += a.x * b.w;
      acc[1][0] += a.y * b.x; acc[1][1] += a.y * b.y; acc[1][2] += a.y * b.z; acc[1][3] += a.y * b.w;
      acc[2][0] += a.z * b.x; acc[2][1] += a.z * b.y; acc[2][2] += a.z * b.z; acc[2][3] += a.z * b.w;
      acc[3][0] += a.w * b.x; acc[3][1] += a.w * b.y; acc[3][2] += a.w * b.z; acc[3][3] += a.w * b.w;
    }
  }

#pragma unroll
  for (int m = 0; m < 4; ++m) {
    float4 st;
    st.x = acc[m][0]; st.y = acc[m][1]; st.z = acc[m][2]; st.w = acc[m][3];
    *reinterpret_cast<float4*>(&Gz[(size_t)(i0 + ty * 4 + m) * A_ + j0 + tx * 4]) = st;
  }
}

// ---------------------------------------------------------------------------
// Kernel 2: per-anchor 3-NN + Cayley-Menger det. One wave per anchor.
// G is in 4 K-parts; dot(i,j) = sum_z Gz[i][j].
// ---------------------------------------------------------------------------
__device__ __forceinline__ void lexmin(float& v, int& j, float ov, int oj) {
  if (ov < v || (ov == v && oj < j)) { v = ov; j = oj; }
}

__global__ __launch_bounds__(64) void nn_det_kernel(
    const float* __restrict__ G, const float* __restrict__ sq,
    float* __restrict__ quality) {
  __shared__ float d2s[16];
  const int i = blockIdx.x;
  const int l = threadIdx.x;
  const float sqi = sq[i];
  const int jb = l * 8;

  float gg[8] = {0.f, 0.f, 0.f, 0.f, 0.f, 0.f, 0.f, 0.f};
#pragma unroll
  for (int z = 0; z < KPARTS; ++z) {
    const float* Grow = G + (size_t)z * A_ * A_ + (size_t)i * A_;
    float4 g0 = *reinterpret_cast<const float4*>(&Grow[jb]);
    float4 g1 = *reinterpret_cast<const float4*>(&Grow[jb + 4]);
    gg[0] += g0.x; gg[1] += g0.y; gg[2] += g0.z; gg[3] += g0.w;
    gg[4] += g1.x; gg[5] += g1.y; gg[6] += g1.z; gg[7] += g1.w;
  }
  float4 s0 = *reinterpret_cast<const float4*>(&sq[jb]);
  float4 s1 = *reinterpret_cast<const float4*>(&sq[jb + 4]);
  float ss[8] = { s0.x, s0.y, s0.z, s0.w, s1.x, s1.y, s1.z, s1.w };

  float dist[8];
#pragma unroll
  for (int q = 0; q < 8; ++q) {
    float d2 = fmaxf(sqi + ss[q] - 2.f * gg[q], 0.f);
    float dd = sqrtf(d2);
    if (jb + q == i) dd += 1e12f;
    dist[q] = dd;
  }

  int nn[NN_];
#pragma unroll
  for (int r = 0; r < NN_; ++r) {
    float bv = 1e30f;
    int bi = 0x7fffffff;
#pragma unroll
    for (int q = 0; q < 8; ++q) lexmin(bv, bi, dist[q], jb + q);
#pragma unroll
    for (int d = 1; d < 64; d <<= 1) {
      float ov = __shfl_xor(bv, d);
      int oi = __shfl_xor(bi, d);
      lexmin(bv, bi, ov, oi);
    }
    nn[r] = bi;
#pragma unroll
    for (int q = 0; q < 8; ++q)
      if (jb + q == bi) dist[q] = 1e30f;
  }

  if (l < 16) {
    const int p = l >> 2, q = l & 3;
    const int pi = (p == 0) ? i : ((p == 1) ? nn[0] : ((p == 2) ? nn[1] : nn[2]));
    const int qi = (q == 0) ? i : ((q == 1) ? nn[0] : ((q == 2) ? nn[1] : nn[2]));
    float d2f;
    if (p == q) {
      d2f = 0.f;
    } else {
      float g = 0.f;
#pragma unroll
      for (int z = 0; z < KPARTS; ++z)
        g += G[(size_t)z * A_ * A_ + (size_t)pi * A_ + qi];
      d2f = sq[pi] + sq[qi] - 2.f * g;
    }
    d2s[l] = d2f;
  }
  __syncthreads();

  if (l == 0) {
    double M[5][5];
    M[0][0] = 0.0;
    for (int q = 1; q < 5; ++q) { M[0][q] = 1.0; M[q][0] = 1.0; }
    for (int p = 0; p < 4; ++p)
      for (int q = 0; q < 4; ++q)
        M[p + 1][q + 1] = (double)d2s[p * 4 + q];

    double det = 1.0;
    for (int c = 0; c < 5; ++c) {
      int piv = c;
      double mx = fabs(M[c][c]);
      for (int r2 = c + 1; r2 < 5; ++r2) {
        double v = fabs(M[r2][c]);
        if (v > mx) { mx = v; piv = r2; }
      }
      if (piv != c) {
        for (int c2 = 0; c2 < 5; ++c2) { double tmp = M[c][c2]; M[c][c2] = M[piv][c2]; M[piv][c2] = tmp; }
        det = -det;
      }
      double pv = M[c][c];
      det *= pv;
      if (pv == 0.0) break;
      for (int r2 = c + 1; r2 < 5; ++r2) {
        double f = M[r2][c] / pv;
        for (int c2 = c; c2 < 5; ++c2) M[r2][c2] -= f * M[c][c2];
      }
    }
    float raw = (float)det;
    float sg = (raw > 0.f) ? 1.f : ((raw < 0.f) ? -1.f : 0.f);
    quality[i] = sg * logf(fabsf(raw) + 1e-12f);
  }
}

// ---------------------------------------------------------------------------
// Kernel 3: normalize quality -> (q - mean) / max(std_ddof1, 1e-8). 1 block.
// ---------------------------------------------------------------------------
__global__ __launch_bounds__(A_) void norm_cm_kernel(
    const float* __restrict__ quality, float* __restrict__ cmn) {
  __shared__ float red[A_];
  const int t = threadIdx.x;
  float q = quality[t];
  red[t] = q;
  __syncthreads();
  for (int s = A_ / 2; s > 0; s >>= 1) {
    if (t < s) red[t] += red[t + s];
    __syncthreads();
  }
  float mean = red[0] * (1.0f / A_);
  __syncthreads();
  float dq = q - mean;
  red[t] = dq * dq;
  __syncthreads();
  for (int s = A_ / 2; s > 0; s >>= 1) {
    if (t < s) red[t] += red[t + s];
    __syncthreads();
  }
  float sd = sqrtf(red[0] * (1.0f / (A_ - 1)));
  sd = fmaxf(sd, 1e-8f);
  cmn[t] = dq / sd;
}

// ---------------------------------------------------------------------------
// Kernel 4 (v3): 512-bucket stable rank + gate MLP + sigmoid.
//  - 512 buckets (9-bit): avg occupancy 1, max ~6.
//  - no cursor array: scatter slot via atomic decrement of hist.
//  - fixed-unroll probe: 8 unconditional LDS reads, ONE waitcnt, predicated
//    compares; fallback loop for len>8 (prob ~1e-6 per bucket).
// ---------------------------------------------------------------------------
__global__ __launch_bounds__(A_) void gate_kernel_v3(
    const float* __restrict__ tri, const float* __restrict__ cmn,
    const float* __restrict__ W1, const float* __restrict__ b1,
    const float* __restrict__ W2, const float* __restrict__ b2,
    float* __restrict__ out) {
  __shared__ int hist[512];
  __shared__ int pref[513];
  __shared__ unsigned long long sorted[520];   // 8-slot pad for OOB-safe probe

  const int n = blockIdx.x;
  const int t = threadIdx.x;

  const float ti = tri[(size_t)n * A_ + t];
  const unsigned long long key =
      ((unsigned long long)__float_as_uint(ti) << 9) | (unsigned)t;
  int b = (int)(ti * 256.0f);                  // monotone in ti (ti in [0,2))
  b = (b < 0) ? 0 : ((b > 511) ? 511 : b);

  hist[t] = 0;
  __syncthreads();
  atomicAdd(&hist[b], 1);
  __syncthreads();

  // exclusive prefix over 512 buckets: wave 0, 8 buckets/lane + shfl scan
  if (t < 64) {
    const int base = t * 8;
    int h[8];
#pragma unroll
    for (int q = 0; q < 8; ++q) h[q] = hist[base + q];
    int s = 0;
#pragma unroll
    for (int q = 0; q < 8; ++q) s += h[q];
    int incl = s;
#pragma unroll
    for (int d = 1; d < 64; d <<= 1) {
      int u = __shfl_up(incl, d);
      if (t >= d) incl += u;
    }
    int ex = incl - s;
#pragma unroll
    for (int q = 0; q < 8; ++q) { pref[base + q] = ex; ex += h[q]; }
  }
  if (t == 0) pref[512] = 512;
  __syncthreads();

  // scatter: slot = pref[b] + (remaining count - 1); destroys hist
  const int start = pref[b];
  const int pos = start + atomicAdd(&hist[b], -1) - 1;
  sorted[pos] = key;
  __syncthreads();

  const int len = pref[b + 1] - start;
  int cnt = start;
#pragma unroll
  for (int m = 0; m < 8; ++m) {
    const unsigned long long v = sorted[start + m];   // unconditional, batched
    cnt += (m < len && v < key) ? 1 : 0;
  }
  if (len > 8) {                                      // ~never taken
    for (int m = 8; m < len; ++m) cnt += (sorted[start + m] < key) ? 1 : 0;
  }
  const float rank = (float)cnt * (1.0f / (A_ - 1));

  const float f0 = cmn[t];
  const float f1 = 1.0f - ti;

  float logit = b2[0];
#pragma unroll
  for (int k = 0; k < 16; ++k) {
    float x = fmaf(W1[k * 3 + 0], f0,
              fmaf(W1[k * 3 + 1], f1,
              fmaf(W1[k * 3 + 2], rank, b1[k])));
    logit = fmaf(W2[k], gelu_erf_fast(x), logit);
  }
  const float eneg = exp2f(logit * -1.44269504088896340736f);
  out[(size_t)n * A_ + t] = __builtin_amdgcn_rcpf(1.0f + eneg);
}

// ---------------------------------------------------------------------------
extern "C" void kernel_launch(void* const* d_in, const int* in_sizes, int n_in,
                              void* d_out, int out_size, void* d_ws, size_t ws_size,
                              hipStream_t stream) {
  // inputs: 0 embedding (unused), 1 anchors, 2 tri, 3 W1, 4 b1, 5 W2, 6 b2
  const float* anchors = (const float*)d_in[1];
  const float* tri     = (const float*)d_in[2];
  const float* W1      = (const float*)d_in[3];
  const float* b1      = (const float*)d_in[4];
  const float* W2      = (const float*)d_in[5];
  const float* b2      = (const float*)d_in[6];
  float* out = (float*)d_out;

  float* G       = (float*)d_ws;                       // KPARTS * A_*A_ (4 MB)
  float* sq      = G + (size_t)KPARTS * A_ * A_;       // A_ floats
  float* quality = sq + A_;                            // A_ floats
  float* cmn     = quality + A_;                       // A_ floats

  sq_kernel<<<A_, 64, 0, stream>>>(anchors, sq);
  gram_tiled_kernel<<<dim3(8, 8, KPARTS), dim3(16, 16), 0, stream>>>(anchors, G);
  nn_det_kernel<<<A_, 64, 0, stream>>>(G, sq, quality);
  norm_cm_kernel<<<1, A_, 0, stream>>>(quality, cmn);
  gate_kernel_v3<<<N_, A_, 0, stream>>>(tri, cmn, W1, b1, W2, b2, out);
}